// Round 1
// baseline (152.368 us; speedup 1.0000x reference)
//
#include <hip/hip_runtime.h>
#include <stdint.h>
#include <math.h>

// ---------------------------------------------------------------------------
// SelfAttention: X[4,2048,1024] f32; Wq/Wk/Wv [1024,128] f32
// Q=XWq K=XWk V=XWv ; O = softmax(QK^T/sqrt(128)) V   (no mask)
// Strategy: bf16 MFMA (16x16x16 _1k shape, documented layout), f32 accum,
// f32 softmax. KV-split flash attention + merge.
// ---------------------------------------------------------------------------

typedef __attribute__((ext_vector_type(4))) float  f32x4;
typedef __attribute__((ext_vector_type(4))) short  s16x4;
typedef __attribute__((ext_vector_type(8))) short  s16x8;
typedef __attribute__((ext_vector_type(4))) float  fl4;

#define MFMA(a,b,c) __builtin_amdgcn_mfma_f32_16x16x16bf16_1k(a,b,c,0,0,0)

__device__ __forceinline__ short f2bf(float f){
  uint32_t u = __builtin_bit_cast(uint32_t, f);
  u = (u + 0x7FFFu + ((u >> 16) & 1u)) >> 16;   // RNE
  return (short)u;
}

#define S_LEN   2048
#define D_IN    1024
#define D_HEAD  128
#define NROWS   8192      // B*S
#define NSPLIT  4
#define KVB     32
#define QBLK    64

// ws layout (bytes)
#define WT_OFF  0u                        // 3*128*1024*2      = 786432
#define Q_OFF   786432u                   // 8192*128*2        = 2097152
#define K_OFF   (786432u + 2097152u)
#define V_OFF   (786432u + 2u*2097152u)
#define OP_OFF  (786432u + 3u*2097152u)   // 4*8192*128*4      = 16777216
#define ML_OFF  (OP_OFF + 16777216u)      // 4*8192*2*4        = 262144
// total ~24.1 MB

// ---------------------------------------------------------------------------
// Kernel 1: W [1024][128] f32  ->  Wt [3][128][1024] bf16  (transpose+convert)
// ---------------------------------------------------------------------------
__global__ __launch_bounds__(256) void wt3_kernel(
    const float* __restrict__ Wq, const float* __restrict__ Wk,
    const float* __restrict__ Wv, short* __restrict__ Wt){
  int i = blockIdx.x * 256 + threadIdx.x;    // < 3*131072
  int m = i >> 17;
  int r = i & 131071;
  int n = r >> 10;          // 0..127
  int k = r & 1023;         // 0..1023
  const float* W = (m == 0) ? Wq : (m == 1 ? Wk : Wv);
  Wt[i] = f2bf(W[k * D_HEAD + n]);
}

// ---------------------------------------------------------------------------
// Kernel 2: projection GEMM.  C[m][n] = sum_k X[m][k] * W[k][n]
// grid (128 m-tiles of 64 rows, 3 matrices). 256 thr = 4 waves (2x2).
// mat 0 -> Q [8192][128] bf16 ; mat 1 -> K ; mat 2 -> V^T [4][128][2048] bf16
// ---------------------------------------------------------------------------
__global__ __launch_bounds__(256) void proj_kernel(
    const float* __restrict__ X, const short* __restrict__ Wt,
    short* __restrict__ Qo, short* __restrict__ Ko, short* __restrict__ Vt){
  const int mt  = blockIdx.x;
  const int mat = blockIdx.y;
  const short* Wm = Wt + mat * 131072;

  __shared__ short Xs[64][40];    // 64x32 tile, pad->row stride 80B (2-way max)
  __shared__ short Ws[128][40];   // 128x32 tile of W^T (row n, col k)

  const int tid  = threadIdx.x;
  const int lane = tid & 63;
  const int wid  = tid >> 6;
  const int wm   = (wid >> 1) * 32;   // wave m offset (0/32)
  const int wn   = (wid & 1) * 64;    // wave n offset (0/64)
  const int lr   = lane & 15;
  const int lg   = lane >> 4;

  f32x4 acc[2][4];
  const f32x4 zero4 = {0.f, 0.f, 0.f, 0.f};
  #pragma unroll
  for (int a = 0; a < 2; a++)
    #pragma unroll
    for (int b2 = 0; b2 < 4; b2++) acc[a][b2] = zero4;

  const int xr = tid >> 2;            // 0..63
  const int xc = (tid & 3) * 8;       // 0,8,16,24
  const int wr = tid >> 1;            // 0..127
  const int wc = (tid & 1) * 16;      // 0,16

  for (int kt = 0; kt < D_IN; kt += 32){
    __syncthreads();
    { // stage X 64x32 f32 -> bf16
      const float* src = X + (size_t)(mt * 64 + xr) * D_IN + kt + xc;
      fl4 a0 = *(const fl4*)src;
      fl4 a1 = *(const fl4*)(src + 4);
      s16x8 v;
      #pragma unroll
      for (int j = 0; j < 4; j++){ v[j] = f2bf(a0[j]); v[j+4] = f2bf(a1[j]); }
      *(s16x8*)&Xs[xr][xc] = v;
    }
    { // stage W^T 128x32 bf16
      const short* src = Wm + (size_t)wr * D_IN + kt + wc;
      s16x8 w0 = *(const s16x8*)src;
      s16x8 w1 = *(const s16x8*)(src + 8);
      *(s16x8*)&Ws[wr][wc]     = w0;
      *(s16x8*)&Ws[wr][wc + 8] = w1;
    }
    __syncthreads();

    #pragma unroll
    for (int kc = 0; kc < 32; kc += 16){
      s16x4 af[2], bf[4];
      #pragma unroll
      for (int mf = 0; mf < 2; mf++)
        af[mf] = *(const s16x4*)&Xs[wm + mf*16 + lr][kc + 4*lg];
      #pragma unroll
      for (int nf = 0; nf < 4; nf++)
        bf[nf] = *(const s16x4*)&Ws[wn + nf*16 + lr][kc + 4*lg];
      #pragma unroll
      for (int mf = 0; mf < 2; mf++)
        #pragma unroll
        for (int nf = 0; nf < 4; nf++)
          acc[mf][nf] = MFMA(af[mf], bf[nf], acc[mf][nf]);
    }
  }

  if (mat < 2){
    short* dst = (mat == 0) ? Qo : Ko;
    #pragma unroll
    for (int mf = 0; mf < 2; mf++)
      #pragma unroll
      for (int nf = 0; nf < 4; nf++)
        #pragma unroll
        for (int r = 0; r < 4; r++){
          int row = mt*64 + wm + mf*16 + 4*lg + r;
          int col = wn + nf*16 + lr;
          dst[(size_t)row * D_HEAD + col] = f2bf(acc[mf][nf][r]);
        }
  } else {
    const int b  = (mt * 64) >> 11;
    const int s0 = (mt * 64) & 2047;
    #pragma unroll
    for (int mf = 0; mf < 2; mf++)
      #pragma unroll
      for (int nf = 0; nf < 4; nf++){
        int dv = wn + nf*16 + lr;
        int s  = s0 + wm + mf*16 + 4*lg;
        s16x4 v;
        #pragma unroll
        for (int r = 0; r < 4; r++) v[r] = f2bf(acc[mf][nf][r]);
        *(s16x4*)&Vt[((size_t)b * D_HEAD + dv) * S_LEN + s] = v;
      }
  }
}

// ---------------------------------------------------------------------------
// Kernel 3: flash attention with KV split.
// grid (NSPLIT, S/QBLK=32, B=4), 256 thr = 4 waves, each wave 16 q rows.
// Swapped QK^T:  S^T = K · Q^T  (A=K rows from LDS, B=Q rows from regs)
// PV:            O^T = V^T · P^T (A=V^T rows from LDS, B=P^T straight from
//                                 the S^T accumulator registers)
// ---------------------------------------------------------------------------
__global__ __launch_bounds__(256) void flash_kernel(
    const short* __restrict__ Q, const short* __restrict__ K,
    const short* __restrict__ Vt, float* __restrict__ Opart,
    float* __restrict__ MLpart){
  const int sp = blockIdx.x;
  const int qt = blockIdx.y;
  const int b  = blockIdx.z;

  __shared__ short Ks[KVB][136];   // 32 x 128 bf16, row stride 272B
  __shared__ short Vs[128][40];    // V^T tile: 128 dv x 32 kv, stride 80B

  const int tid  = threadIdx.x;
  const int lane = tid & 63;
  const int w    = tid >> 6;
  const int lr   = lane & 15;
  const int lg   = lane >> 4;

  const int qrow = qt * QBLK + w * 16 + lr;           // row within batch
  const short* Qr = Q + (size_t)(b * S_LEN + qrow) * D_HEAD + 4 * lg;
  s16x4 qf[8];
  #pragma unroll
  for (int c = 0; c < 8; c++) qf[c] = *(const s16x4*)(Qr + c * 16);

  const f32x4 zero4 = {0.f, 0.f, 0.f, 0.f};
  f32x4 o[8];
  #pragma unroll
  for (int t = 0; t < 8; t++) o[t] = zero4;
  float m_run = -INFINITY, l_run = 0.0f;

  const int kr = tid >> 3, kc = (tid & 7) * 16;   // K staging coords
  const int vr = tid >> 1, vc = (tid & 1) * 16;   // V staging coords
  const float scale = 0.08838834764831845f;       // 1/sqrt(128)

  const int kv_beg = sp * (S_LEN / NSPLIT);
  const int kv_end = kv_beg + (S_LEN / NSPLIT);
  for (int kv0 = kv_beg; kv0 < kv_end; kv0 += KVB){
    __syncthreads();
    { // stage K tile 32x128 and V^T tile 128x32
      const short* src = K + (size_t)(b * S_LEN + kv0 + kr) * D_HEAD + kc;
      s16x8 k0 = *(const s16x8*)src;
      s16x8 k1 = *(const s16x8*)(src + 8);
      *(s16x8*)&Ks[kr][kc]     = k0;
      *(s16x8*)&Ks[kr][kc + 8] = k1;
      const short* vsrc = Vt + ((size_t)b * D_HEAD + vr) * S_LEN + kv0 + vc;
      s16x8 v0 = *(const s16x8*)vsrc;
      s16x8 v1 = *(const s16x8*)(vsrc + 8);
      *(s16x8*)&Vs[vr][vc]     = v0;
      *(s16x8*)&Vs[vr][vc + 8] = v1;
    }
    __syncthreads();

    // S^T = K * Q^T : lane holds S[kv=4*lg+r (+16*t)][q=lr]
    f32x4 sa[2];
    sa[0] = zero4; sa[1] = zero4;
    #pragma unroll
    for (int c = 0; c < 8; c++){
      #pragma unroll
      for (int t = 0; t < 2; t++){
        s16x4 ka = *(const s16x4*)&Ks[t*16 + lr][c*16 + 4*lg];
        sa[t] = MFMA(ka, qf[c], sa[t]);
      }
    }

    // online softmax along kv (4 dup lanes share q-row: xor 16 / 32)
    float p[8]; float mx = -INFINITY;
    #pragma unroll
    for (int t = 0; t < 2; t++)
      #pragma unroll
      for (int r = 0; r < 4; r++){
        float v = sa[t][r] * scale;
        p[t*4 + r] = v;
        mx = fmaxf(mx, v);
      }
    mx = fmaxf(mx, __shfl_xor(mx, 16));
    mx = fmaxf(mx, __shfl_xor(mx, 32));
    float m_new = fmaxf(m_run, mx);
    float alpha = __expf(m_run - m_new);   // first iter: exp(-inf)=0
    float lsum = 0.0f;
    #pragma unroll
    for (int j = 0; j < 8; j++){ p[j] = __expf(p[j] - m_new); lsum += p[j]; }
    lsum += __shfl_xor(lsum, 16);
    lsum += __shfl_xor(lsum, 32);
    l_run = l_run * alpha + lsum;
    m_run = m_new;

    s16x4 pb0, pb1;
    #pragma unroll
    for (int r = 0; r < 4; r++){ pb0[r] = f2bf(p[r]); pb1[r] = f2bf(p[4 + r]); }
    #pragma unroll
    for (int t = 0; t < 8; t++) o[t] *= alpha;

    // O^T += V^T * P^T
    #pragma unroll
    for (int dt = 0; dt < 8; dt++){
      s16x4 va0 = *(const s16x4*)&Vs[dt*16 + lr][4*lg];
      s16x4 va1 = *(const s16x4*)&Vs[dt*16 + lr][16 + 4*lg];
      o[dt] = MFMA(va0, pb0, o[dt]);
      o[dt] = MFMA(va1, pb1, o[dt]);
    }
  }

  const size_t grow = (size_t)b * S_LEN + qrow;
  float* Op = Opart + ((size_t)sp * NROWS + grow) * D_HEAD + 4 * lg;
  #pragma unroll
  for (int dt = 0; dt < 8; dt++)
    *(f32x4*)(Op + dt * 16) = o[dt];
  if (lane < 16){
    float* ml = MLpart + ((size_t)sp * NROWS + grow) * 2;
    ml[0] = m_run; ml[1] = l_run;
  }
}

// ---------------------------------------------------------------------------
// Kernel 4: merge the NSPLIT partials.
// ---------------------------------------------------------------------------
__global__ __launch_bounds__(256) void merge_kernel(
    const float* __restrict__ Opart, const float* __restrict__ MLpart,
    float* __restrict__ out){
  int idx = blockIdx.x * 256 + threadIdx.x;    // < 8192*128
  int row = idx >> 7;
  float m[NSPLIT], l[NSPLIT];
  float M = -INFINITY;
  #pragma unroll
  for (int s = 0; s < NSPLIT; s++){
    m[s] = MLpart[((size_t)s * NROWS + row) * 2 + 0];
    l[s] = MLpart[((size_t)s * NROWS + row) * 2 + 1];
    M = fmaxf(M, m[s]);
  }
  float L = 0.f, val = 0.f;
  #pragma unroll
  for (int s = 0; s < NSPLIT; s++){
    float e = __expf(m[s] - M);
    L   += l[s] * e;
    val += Opart[(size_t)s * NROWS * D_HEAD + idx] * e;
  }
  out[idx] = val / L;
}

// ---------------------------------------------------------------------------
extern "C" void kernel_launch(void* const* d_in, const int* in_sizes, int n_in,
                              void* d_out, int out_size, void* d_ws, size_t ws_size,
                              hipStream_t stream){
  const float* X  = (const float*)d_in[0];
  const float* Wq = (const float*)d_in[1];
  const float* Wk = (const float*)d_in[2];
  const float* Wv = (const float*)d_in[3];
  char* ws = (char*)d_ws;
  short* Wt = (short*)(ws + WT_OFF);
  short* Qp = (short*)(ws + Q_OFF);
  short* Kp = (short*)(ws + K_OFF);
  short* Vt = (short*)(ws + V_OFF);
  float* Op = (float*)(ws + OP_OFF);
  float* Ml = (float*)(ws + ML_OFF);
  float* out = (float*)d_out;

  wt3_kernel  <<<dim3(1536),          dim3(256), 0, stream>>>(Wq, Wk, Wv, Wt);
  proj_kernel <<<dim3(128, 3),        dim3(256), 0, stream>>>(X, Wt, Qp, Kp, Vt);
  flash_kernel<<<dim3(NSPLIT, 32, 4), dim3(256), 0, stream>>>(Qp, Kp, Vt, Op, Ml);
  merge_kernel<<<dim3(4096),          dim3(256), 0, stream>>>(Op, Ml, out);
}

// Round 4
// 128.568 us; speedup vs baseline: 1.1851x; 1.1851x over previous
//
#include <hip/hip_runtime.h>
#include <stdint.h>
#include <math.h>

// ---------------------------------------------------------------------------
// SelfAttention: X[4,2048,1024] f32; Wq/Wk/Wv [1024,128] f32
// O = softmax(XWq (XWk)^T / sqrt(128)) XWv      (no mask)
// bf16 MFMA: 16x16x32 for proj & QK^T, 16x16x16 for PV (P feeds B directly).
// KV-split flash attention + merge. Register prefetch (T14) on both GEMM
// loops. Scale folded into Wq. Defer-max (T13) softmax.
// ---------------------------------------------------------------------------

typedef __attribute__((ext_vector_type(4))) float  f32x4;
typedef __attribute__((ext_vector_type(4))) short  s16x4;
typedef __attribute__((ext_vector_type(8))) short  s16x8;
typedef __attribute__((ext_vector_type(4))) float  fl4;

#define MFMA16(a,b,c) __builtin_amdgcn_mfma_f32_16x16x16bf16_1k(a,b,c,0,0,0)
#define MFMA32(a,b,c) __builtin_amdgcn_mfma_f32_16x16x32_bf16(a,b,c,0,0,0)

__device__ __forceinline__ short f2bf(float f){
  uint32_t u = __builtin_bit_cast(uint32_t, f);
  u = (u + 0x7FFFu + ((u >> 16) & 1u)) >> 16;   // RNE
  return (short)u;
}

#define S_LEN   2048
#define D_IN    1024
#define D_HEAD  128
#define NROWS   8192      // B*S
#define NSPLIT  4
#define KVB     64
#define KVPER   (S_LEN / NSPLIT)   // 512
#define NT      (KVPER / KVB)      // 8

// ws layout (bytes)
#define WT_OFF  0u                        // 3*128*1024*2      = 786432
#define Q_OFF   786432u                   // 8192*128*2        = 2097152
#define K_OFF   (786432u + 2097152u)
#define V_OFF   (786432u + 2u*2097152u)
#define OP_OFF  (786432u + 3u*2097152u)   // 4*8192*128*4      = 16777216
#define ML_OFF  (OP_OFF + 16777216u)      // 4*8192*2*4        = 262144
// total ~24.1 MB

// ---------------------------------------------------------------------------
// Kernel 1: W [1024][128] f32 -> Wt [3][128][1024] bf16 (transpose+convert).
// 1/sqrt(128) folded into Wq.
// ---------------------------------------------------------------------------
__global__ __launch_bounds__(256) void wt3_kernel(
    const float* __restrict__ Wq, const float* __restrict__ Wk,
    const float* __restrict__ Wv, short* __restrict__ Wt){
  int i = blockIdx.x * 256 + threadIdx.x;    // < 3*131072
  int m = i >> 17;
  int r = i & 131071;
  int n = r >> 10;          // 0..127
  int k = r & 1023;         // 0..1023
  const float* W = (m == 0) ? Wq : (m == 1 ? Wk : Wv);
  float v = W[k * D_HEAD + n];
  if (m == 0) v *= 0.08838834764831845f;
  Wt[i] = f2bf(v);
}

// ---------------------------------------------------------------------------
// Kernel 2: projection GEMM. grid (256 m-tiles of 32 rows, 3 mats), 4 waves.
// Block tile 32x128, wave tile 16x64, BK=64, x32 MFMA, reg prefetch.
// mat 0 -> Q bf16 [8192][128]; 1 -> K; 2 -> V^T bf16 [4][128][2048]
// ---------------------------------------------------------------------------
__global__ __launch_bounds__(256) void proj_kernel(
    const float* __restrict__ X, const short* __restrict__ Wt,
    short* __restrict__ Qo, short* __restrict__ Ko, short* __restrict__ Vt){
  const int mt  = blockIdx.x;     // 0..255 (32-row tiles)
  const int mat = blockIdx.y;
  const short* Wm = Wt + mat * 131072;

  __shared__ short Xs[32][72];    // 32x64 bf16 tile (pad 144B stride)
  __shared__ short Ws[128][72];   // 128x64 bf16 tile of W^T

  const int tid  = threadIdx.x;
  const int lane = tid & 63;
  const int wid  = tid >> 6;
  const int wm   = (wid >> 1) * 16;   // 0/16
  const int wn   = (wid & 1) * 64;    // 0/64
  const int lr   = lane & 15;
  const int lg8  = (lane >> 4) * 8;

  const f32x4 zero4 = {0.f, 0.f, 0.f, 0.f};
  f32x4 acc[4];
  #pragma unroll
  for (int n = 0; n < 4; n++) acc[n] = zero4;

  // staging coords
  const int xr = tid >> 3, xc = (tid & 7) * 8;     // X: 32x64, 8 f32/thread
  const int wr = tid >> 1, wc = (tid & 1) * 32;    // W: 128x64, 32 bf16/thread

  const float* xsrc0 = X + (size_t)(mt * 32 + xr) * D_IN + xc;
  const short* wsrc0 = Wm + (size_t)wr * D_IN + wc;

  fl4   xA, xB;
  s16x8 wR[4];

  // preload k-step 0
  xA = *(const fl4*)(xsrc0);
  xB = *(const fl4*)(xsrc0 + 4);
  #pragma unroll
  for (int j = 0; j < 4; j++) wR[j] = *(const s16x8*)(wsrc0 + 8 * j);

  #pragma unroll 1
  for (int kt = 0; kt < D_IN; kt += 64){
    { // write staged tile
      s16x8 v;
      #pragma unroll
      for (int j = 0; j < 4; j++){ v[j] = f2bf(xA[j]); v[j+4] = f2bf(xB[j]); }
      *(s16x8*)&Xs[xr][xc] = v;
      #pragma unroll
      for (int j = 0; j < 4; j++) *(s16x8*)&Ws[wr][wc + 8*j] = wR[j];
    }
    __syncthreads();

    // prefetch next k-step
    if (kt + 64 < D_IN){
      xA = *(const fl4*)(xsrc0 + kt + 64);
      xB = *(const fl4*)(xsrc0 + kt + 68);
      #pragma unroll
      for (int j = 0; j < 4; j++) wR[j] = *(const s16x8*)(wsrc0 + kt + 64 + 8*j);
    }

    #pragma unroll
    for (int kc = 0; kc < 64; kc += 32){
      s16x8 af = *(const s16x8*)&Xs[wm + lr][kc + lg8];
      #pragma unroll
      for (int n = 0; n < 4; n++){
        s16x8 bf = *(const s16x8*)&Ws[wn + n*16 + lr][kc + lg8];
        acc[n] = MFMA32(af, bf, acc[n]);
      }
    }
    __syncthreads();
  }

  const int lg4 = (lane >> 4) * 4;
  if (mat < 2){
    short* dst = (mat == 0) ? Qo : Ko;
    #pragma unroll
    for (int n = 0; n < 4; n++){
      int col = wn + n*16 + lr;
      #pragma unroll
      for (int r = 0; r < 4; r++){
        int row = mt*32 + wm + lg4 + r;
        dst[(size_t)row * D_HEAD + col] = f2bf(acc[n][r]);
      }
    }
  } else {
    const int b  = (mt * 32) >> 11;
    const int s0 = (mt * 32) & 2047;
    #pragma unroll
    for (int n = 0; n < 4; n++){
      int dv = wn + n*16 + lr;
      int s  = s0 + wm + lg4;
      s16x4 v;
      #pragma unroll
      for (int r = 0; r < 4; r++) v[r] = f2bf(acc[n][r]);
      *(s16x4*)&Vt[((size_t)b * D_HEAD + dv) * S_LEN + s] = v;
    }
  }
}

// ---------------------------------------------------------------------------
// Kernel 3: flash attention, KV split. grid (NSPLIT, 32, 4), 4 waves.
// Wave = 16 q rows. KVB=64, x32 QK^T, x16 PV, reg prefetch, defer-max.
// ---------------------------------------------------------------------------
__global__ __launch_bounds__(256) void flash_kernel(
    const short* __restrict__ Q, const short* __restrict__ K,
    const short* __restrict__ Vt, float* __restrict__ Opart,
    float* __restrict__ MLpart){
  const int sp = blockIdx.x;
  const int qt = blockIdx.y;
  const int b  = blockIdx.z;

  __shared__ short Ks[KVB][136];   // 64 x 128 bf16 (272B stride)
  __shared__ short Vs[128][72];    // V^T tile: 128 dv x 64 kv (144B stride)

  const int tid  = threadIdx.x;
  const int lane = tid & 63;
  const int w    = tid >> 6;
  const int lr   = lane & 15;
  const int lg   = lane >> 4;

  // Q fragments (B operand of QK^T): row q=lr, 8 contiguous d at c*32+8*lg
  const int qrow = qt * 64 + w * 16 + lr;
  const short* Qr = Q + (size_t)(b * S_LEN + qrow) * D_HEAD + 8 * lg;
  s16x8 qf[4];
  #pragma unroll
  for (int c = 0; c < 4; c++) qf[c] = *(const s16x8*)(Qr + c * 32);

  const f32x4 zero4 = {0.f, 0.f, 0.f, 0.f};
  f32x4 o[8];
  #pragma unroll
  for (int t = 0; t < 8; t++) o[t] = zero4;
  float m_run = -INFINITY, l_run = 0.0f;

  const short* Kb = K  + (size_t)b * S_LEN * D_HEAD;
  const short* Vb = Vt + (size_t)b * D_HEAD * S_LEN;
  const int kr = tid >> 2, kc = (tid & 3) * 32;   // K tile 64x128
  const int vr = tid >> 1, vc = (tid & 1) * 32;   // V^T tile 128x64

  s16x8 kR[4], vR[4];
  const int kv_beg = sp * KVPER;

  { // preload tile 0
    const short* ks = Kb + (size_t)(kv_beg + kr) * D_HEAD + kc;
    const short* vs = Vb + (size_t)vr * S_LEN + kv_beg + vc;
    #pragma unroll
    for (int j = 0; j < 4; j++){
      kR[j] = *(const s16x8*)(ks + 8*j);
      vR[j] = *(const s16x8*)(vs + 8*j);
    }
  }
  #pragma unroll
  for (int j = 0; j < 4; j++){
    *(s16x8*)&Ks[kr][kc + 8*j] = kR[j];
    *(s16x8*)&Vs[vr][vc + 8*j] = vR[j];
  }
  __syncthreads();

  #pragma unroll 1
  for (int it = 0; it < NT; ++it){
    // prefetch next tile into regs (global latency hides under compute)
    if (it + 1 < NT){
      int kv0 = kv_beg + (it + 1) * KVB;
      const short* ks = Kb + (size_t)(kv0 + kr) * D_HEAD + kc;
      const short* vs = Vb + (size_t)vr * S_LEN + kv0 + vc;
      #pragma unroll
      for (int j = 0; j < 4; j++){
        kR[j] = *(const s16x8*)(ks + 8*j);
        vR[j] = *(const s16x8*)(vs + 8*j);
      }
    }

    // S^T = K * Q^T (x32): lane holds S[kv = 4*lg+r + 16*t][q = lr]
    f32x4 sa[4];
    #pragma unroll
    for (int t = 0; t < 4; t++) sa[t] = zero4;
    #pragma unroll
    for (int c = 0; c < 4; c++){
      #pragma unroll
      for (int t = 0; t < 4; t++){
        s16x8 ka = *(const s16x8*)&Ks[t*16 + lr][c*32 + 8*lg];
        sa[t] = MFMA32(ka, qf[c], sa[t]);
      }
    }

    // online softmax (scale already folded into Wq)
    float p[16]; float mx = -INFINITY;
    #pragma unroll
    for (int t = 0; t < 4; t++)
      #pragma unroll
      for (int r = 0; r < 4; r++){
        p[t*4 + r] = sa[t][r];
        mx = fmaxf(mx, sa[t][r]);
      }
    mx = fmaxf(mx, __shfl_xor(mx, 16));
    mx = fmaxf(mx, __shfl_xor(mx, 32));
    if (!__all(mx <= m_run + 8.0f)){       // defer-max: rescale rarely
      float m_new = fmaxf(m_run, mx);
      float alpha = __expf(m_run - m_new); // first tile: exp(-inf)=0
      l_run *= alpha;
      #pragma unroll
      for (int t = 0; t < 8; t++) o[t] *= alpha;
      m_run = m_new;
    }
    float lsum = 0.0f;
    #pragma unroll
    for (int j = 0; j < 16; j++){ p[j] = __expf(p[j] - m_run); lsum += p[j]; }
    lsum += __shfl_xor(lsum, 16);
    lsum += __shfl_xor(lsum, 32);
    l_run += lsum;

    s16x4 pb[4];
    #pragma unroll
    for (int t = 0; t < 4; t++)
      #pragma unroll
      for (int r = 0; r < 4; r++) pb[t][r] = f2bf(p[t*4 + r]);

    // O^T += V^T * P^T (x16): A rows = dv, B = P straight from regs
    #pragma unroll
    for (int dt = 0; dt < 8; dt++){
      #pragma unroll
      for (int t = 0; t < 4; t++){
        s16x4 va = *(const s16x4*)&Vs[dt*16 + lr][t*16 + 4*lg];
        o[dt] = MFMA16(va, pb[t], o[dt]);
      }
    }

    if (it + 1 < NT){
      __syncthreads();                 // all waves done reading LDS
      #pragma unroll
      for (int j = 0; j < 4; j++){
        *(s16x8*)&Ks[kr][kc + 8*j] = kR[j];
        *(s16x8*)&Vs[vr][vc + 8*j] = vR[j];
      }
      __syncthreads();                 // LDS ready
    }
  }

  const size_t grow = (size_t)b * S_LEN + qrow;
  float* Op = Opart + ((size_t)sp * NROWS + grow) * D_HEAD + 4 * lg;
  #pragma unroll
  for (int dt = 0; dt < 8; dt++)
    *(f32x4*)(Op + dt * 16) = o[dt];
  if (lg == 0){
    float* ml = MLpart + ((size_t)sp * NROWS + grow) * 2;
    ml[0] = m_run; ml[1] = l_run;
  }
}

// ---------------------------------------------------------------------------
// Kernel 4: merge the NSPLIT partials.
// ---------------------------------------------------------------------------
__global__ __launch_bounds__(256) void merge_kernel(
    const float* __restrict__ Opart, const float* __restrict__ MLpart,
    float* __restrict__ out){
  int idx = blockIdx.x * 256 + threadIdx.x;    // < 8192*128
  int row = idx >> 7;
  float m[NSPLIT], l[NSPLIT];
  float M = -INFINITY;
  #pragma unroll
  for (int s = 0; s < NSPLIT; s++){
    m[s] = MLpart[((size_t)s * NROWS + row) * 2 + 0];
    l[s] = MLpart[((size_t)s * NROWS + row) * 2 + 1];
    M = fmaxf(M, m[s]);
  }
  float L = 0.f, val = 0.f;
  #pragma unroll
  for (int s = 0; s < NSPLIT; s++){
    float e = __expf(m[s] - M);
    L   += l[s] * e;
    val += Opart[(size_t)s * NROWS * D_HEAD + idx] * e;
  }
  out[idx] = val / L;
}

// ---------------------------------------------------------------------------
extern "C" void kernel_launch(void* const* d_in, const int* in_sizes, int n_in,
                              void* d_out, int out_size, void* d_ws, size_t ws_size,
                              hipStream_t stream){
  const float* X  = (const float*)d_in[0];
  const float* Wq = (const float*)d_in[1];
  const float* Wk = (const float*)d_in[2];
  const float* Wv = (const float*)d_in[3];
  char* ws = (char*)d_ws;
  short* Wt = (short*)(ws + WT_OFF);
  short* Qp = (short*)(ws + Q_OFF);
  short* Kp = (short*)(ws + K_OFF);
  short* Vt = (short*)(ws + V_OFF);
  float* Op = (float*)(ws + OP_OFF);
  float* Ml = (float*)(ws + ML_OFF);
  float* out = (float*)d_out;

  wt3_kernel  <<<dim3(1536),          dim3(256), 0, stream>>>(Wq, Wk, Wv, Wt);
  proj_kernel <<<dim3(256, 3),        dim3(256), 0, stream>>>(X, Wt, Qp, Kp, Vt);
  flash_kernel<<<dim3(NSPLIT, 32, 4), dim3(256), 0, stream>>>(Qp, Kp, Vt, Op, Ml);
  merge_kernel<<<dim3(4096),          dim3(256), 0, stream>>>(Op, Ml, out);
}